// Round 12
// baseline (370.101 us; speedup 1.0000x reference)
//
#include <hip/hip_runtime.h>
#include <hip/hip_bf16.h>

typedef __hip_bfloat16 bf16;
typedef unsigned short ushort_t;
typedef __attribute__((ext_vector_type(8))) short short8;
typedef __attribute__((ext_vector_type(4))) float fx4;

#define BB 32
#define NN 128
#define FF 9
#define EE 8
#define HH 128
#define HD 256
#define NHEAD 4
#define DHEAD 64

__device__ __forceinline__ float us2f(ushort_t u) {
    return __uint_as_float(((unsigned int)u) << 16);
}
__device__ __forceinline__ ushort_t f2us_tr(float f) {
    return (ushort_t)(__float_as_uint(f) >> 16);
}

__global__ void TransformerConvNet_85315230367963_kernel() {}

__global__ void k_sent(float* out, float val) {
    out[blockIdx.x * 256 + threadIdx.x] = val;
}

__global__ void k_zero(float* p) {
    p[blockIdx.x * 256 + threadIdx.x] = 0.f;
}

// ---------------- K1: adjv + adjvT (masked) — R10 version ----------------
__global__ void k_adjv(const float* adj, float* adjv, float* adjvT) {
    int b = blockIdx.x;            // 32
    const float* src = adj + b * NN * NN;
    float* d1 = adjv + b * NN * NN;
    float* d2 = adjvT + b * NN * NN;
    for (int i = threadIdx.x; i < NN * NN; i += 256) {
        float a = src[i];
        d1[i] = (a > 0.f && a < 1.0f) ? a : 0.f;
    }
    for (int i = threadIdx.x; i < NN * NN; i += 256) {
        int t = i >> 7, s = i & 127;
        float a = src[s * NN + t];
        d2[i] = (a > 0.f && a < 1.0f) ? a : 0.f;   // adjvT[t][s]
    }
}

// ---------------- K2: base[bs][c] = src(bs) @ W1[:17] + b1 ----------------
__global__ void k_base(const float* nf, const int* et, const float* emb,
                       const float* W1, const float* b1, float* base) {
    int bs = blockIdx.x;
    int c = threadIdx.x;
    int ty = et[bs];
    float acc = b1[c];
    for (int f = 0; f < FF; f++)
        acc += nf[bs * FF + f] * W1[f * HH + c];
    for (int e = 0; e < EE; e++)
        acc += emb[ty * EE + e] * W1[(FF + e) * HH + c];
    base[bs * HH + c] = acc;
}

// ---------------- K_prep: Wh' = g1*Wh split bf16 hi/lo, swizzled ----------
__global__ void k_prep(const float* Wh, const float* g1, const float* be1,
                       const float* bh, ushort_t* BhiG, ushort_t* BloG,
                       float* W1s, float* cbv) {
    int n = blockIdx.x;      // 0..127
    int t = threadIdx.x;     // 0..63
    int sw = 8 * (n & 15);
    float s1 = 0.f, s2 = 0.f;
    for (int kk = 0; kk < 2; kk++) {
        int k = t + kk * 64;
        float w = Wh[k * HH + n];
        float wp = g1[k] * w;
        ushort_t hb = f2us_tr(wp);
        float lo = wp - us2f(hb);
        BhiG[n * HH + (k ^ sw)] = hb;
        BloG[n * HH + (k ^ sw)] = f2us_tr(lo);
        s1 += wp;
        s2 += be1[k] * w;
    }
    for (int m = 1; m < 64; m <<= 1) {
        s1 += __shfl_xor(s1, m);
        s2 += __shfl_xor(s2, m);
    }
    if (t == 0) { W1s[n] = s1; cbv[n] = s2 + bh[n]; }
}

// ---------------- K_prepw: split 4 qkvs weight mats into bf16 hi/lo -------
__global__ void k_prepw(const float* W0, const float* W1p, const float* W2p,
                        const float* W3p, int IN, ushort_t* Whi, ushort_t* Wlo) {
    int blk = blockIdx.x;             // 4*256
    int mat = blk >> 8, n = blk & 255;
    const float* W = (mat == 0) ? W0 : (mat == 1) ? W1p : (mat == 2) ? W2p : W3p;
    ushort_t* hi = Whi + mat * 256 * IN;
    ushort_t* lo = Wlo + mat * 256 * IN;
    int sw = 8 * (n & 15);
    for (int k = threadIdx.x; k < IN; k += 64) {
        float w = W[k * HD + n];
        ushort_t hb = f2us_tr(w);
        float l = w - us2f(hb);
        hi[n * IN + (k ^ sw)] = hb;
        lo[n * IN + (k ^ sw)] = f2us_tr(l);
    }
}

// ---------------- K3: embed conv MFMA — R10 structure + grouped loads -----
__global__ void __launch_bounds__(256) k_econv_mfma(
    const float* adjv, const float* base, const float* W1,
    const ushort_t* BhiG, const ushort_t* BloG,
    const float* W1s, const float* cbv,
    const float* ghp, const float* behp, float* x0)
{
    __shared__ __align__(16) ushort_t Bhi[HH * HH];
    __shared__ __align__(16) ushort_t Blo[HH * HH];

    int blk = blockIdx.x;
    int b  = blk >> 4;
    int tt = (blk >> 1) & 7;
    int sh = blk & 1;
    int t0 = tt * 16;
    int tid = threadIdx.x;
    int wv  = tid >> 6;
    int lane = tid & 63;
    int nl = lane & 15;
    int quad = lane >> 4;

    {
        const uint4* srcH = (const uint4*)BhiG;
        const uint4* srcL = (const uint4*)BloG;
        uint4* dstH = (uint4*)Bhi;
        uint4* dstL = (uint4*)Blo;
        for (int i = tid; i < HH * HH / 8; i += 256) {
            dstH[i] = srcH[i];
            dstL[i] = srcL[i];
        }
    }

    float W1s_r[8], cb_r[8], gh_r[8], beh_r[8];
#pragma unroll
    for (int tile = 0; tile < 8; tile++) {
        int c = tile * 16 + nl;
        W1s_r[tile] = W1s[c];
        cb_r[tile]  = cbv[c];
        gh_r[tile]  = ghp[c];
        beh_r[tile] = behp[c];
    }
    float w17v[4][8];
#pragma unroll
    for (int st = 0; st < 4; st++) {
        const float* p = W1 + 17 * HH + quad * 8 + 32 * st;
        float4 a = *(const float4*)p;
        float4 bq = *(const float4*)(p + 4);
        w17v[st][0] = a.x;  w17v[st][1] = a.y;  w17v[st][2] = a.z;  w17v[st][3] = a.w;
        w17v[st][4] = bq.x; w17v[st][5] = bq.y; w17v[st][6] = bq.z; w17v[st][7] = bq.w;
    }

    fx4 xacc[8];
#pragma unroll
    for (int tile = 0; tile < 8; tile++) xacc[tile] = (fx4){0.f, 0.f, 0.f, 0.f};

    __syncthreads();

    int sBase = sh * 64 + wv * 16;
    float av_c = adjv[(b * NN + sBase) * NN + t0 + nl];   // rolling prefetch

    for (int i = 0; i < 16; i++) {
        int s = sBase + i;
        float av_n = (i < 15) ? adjv[(b * NN + s + 1) * NN + t0 + nl] : 0.f;
        const float* brow = base + (b * NN + s) * HH;
        float avv = av_c;

        short8 Ahi[4], Alo[4];
        float sm = 0.f, s2 = 0.f;
#pragma unroll
        for (int st = 0; st < 4; st++) {
            const float* p = brow + quad * 8 + 32 * st;
            float4 b0 = *(const float4*)p;
            float4 b1q = *(const float4*)(p + 4);
            float h[8] = {b0.x, b0.y, b0.z, b0.w, b1q.x, b1q.y, b1q.z, b1q.w};
            short8 ah, al;
#pragma unroll
            for (int j = 0; j < 8; j++) {
                float v = fmaxf(h[j] + avv * w17v[st][j], 0.f);
                sm += v; s2 += v * v;
                ushort_t hb = f2us_tr(v);
                float lo = v - us2f(hb);
                ah[j] = (short)hb;
                al[j] = (short)f2us_tr(lo);
            }
            Ahi[st] = ah; Alo[st] = al;
        }
        sm += __shfl_xor(sm, 16); sm += __shfl_xor(sm, 32);
        s2 += __shfl_xor(s2, 16); s2 += __shfl_xor(s2, 32);
        float m1 = sm * (1.f / 128.f);
        float r1 = rsqrtf(s2 * (1.f / 128.f) - m1 * m1 + 1e-5f);

        float m1d[4], r1d[4], avd[4];
#pragma unroll
        for (int r = 0; r < 4; r++) {
            int src = quad * 4 + r;
            m1d[r] = __shfl(m1, src);
            r1d[r] = __shfl(r1, src);
            avd[r] = __shfl(avv, src);
        }

        fx4 G[8];
#pragma unroll
        for (int tile = 0; tile < 8; tile++) G[tile] = (fx4){0.f, 0.f, 0.f, 0.f};
#pragma unroll
        for (int st = 0; st < 4; st++) {
            int kx = (quad * 8 + 32 * st) ^ (nl * 8);
#pragma unroll
            for (int g = 0; g < 2; g++) {
                // grouped loads (8 frags) then 12 MFMAs — same operands/order
                short8 bh8[4], bl8[4];
#pragma unroll
                for (int t4 = 0; t4 < 4; t4++) {
                    int off = ((g * 4 + t4) * 16 + nl) * HH + kx;
                    bh8[t4] = *(const short8*)(&Bhi[off]);
                    bl8[t4] = *(const short8*)(&Blo[off]);
                }
#pragma unroll
                for (int t4 = 0; t4 < 4; t4++) {
                    int tile = g * 4 + t4;
                    G[tile] = __builtin_amdgcn_mfma_f32_16x16x32_bf16(Ahi[st], bh8[t4], G[tile], 0, 0, 0);
                    G[tile] = __builtin_amdgcn_mfma_f32_16x16x32_bf16(Alo[st], bh8[t4], G[tile], 0, 0, 0);
                    G[tile] = __builtin_amdgcn_mfma_f32_16x16x32_bf16(Ahi[st], bl8[t4], G[tile], 0, 0, 0);
                }
            }
        }

        float sm2[4] = {0.f, 0.f, 0.f, 0.f}, ss2[4] = {0.f, 0.f, 0.f, 0.f};
#pragma unroll
        for (int tile = 0; tile < 8; tile++) {
#pragma unroll
            for (int r = 0; r < 4; r++) {
                float h2 = fmaxf(r1d[r] * (G[tile][r] - m1d[r] * W1s_r[tile]) + cb_r[tile], 0.f);
                G[tile][r] = h2;
                sm2[r] += h2; ss2[r] += h2 * h2;
            }
        }
#pragma unroll
        for (int r = 0; r < 4; r++) {
#pragma unroll
            for (int m = 1; m < 16; m <<= 1) {
                sm2[r] += __shfl_xor(sm2[r], m);
                ss2[r] += __shfl_xor(ss2[r], m);
            }
        }
        float mean2[4], r2v[4];
#pragma unroll
        for (int r = 0; r < 4; r++) {
            mean2[r] = sm2[r] * (1.f / 128.f);
            float var = ss2[r] * (1.f / 128.f) - mean2[r] * mean2[r];
            r2v[r] = rsqrtf(var + 1e-5f);
        }
#pragma unroll
        for (int tile = 0; tile < 8; tile++) {
#pragma unroll
            for (int r = 0; r < 4; r++) {
                float h2n = (G[tile][r] - mean2[r]) * r2v[r] * gh_r[tile] + beh_r[tile];
                if (avd[r] != 0.f) xacc[tile][r] += h2n;
            }
        }
        av_c = av_n;
    }

#pragma unroll
    for (int tile = 0; tile < 8; tile++)
#pragma unroll
        for (int r = 0; r < 4; r++)
            atomicAdd(&x0[(b * NN + t0 + quad * 4 + r) * HH + tile * 16 + nl], xacc[tile][r]);
}

// ---------------- K5: qkvs via MFMA — R10 structure + grouped loads -------
template <int IN>
__global__ void __launch_bounds__(256) k_qkvs_mfma(
    const float* x, const ushort_t* Whi, const ushort_t* Wlo,
    const float* b0, const float* b1, const float* b2, const float* b3,
    float* q, float* skipo,
    ushort_t* khi, ushort_t* klo, ushort_t* vThi, ushort_t* vTlo)
{
    const int ST = IN / 32;
    int blk = blockIdx.x;
    int m0 = (blk >> 2) * 64;
    int nsl = blk & 3;
    int tid = threadIdx.x;
    int wv = tid >> 6;
    int lane = tid & 63;
    int nl = lane & 15;
    int quad = lane >> 4;
    int row = m0 + wv * 16 + nl;

    short8 Ahi[ST], Alo[ST];
    const float* xrow = x + (long)row * IN;
#pragma unroll
    for (int st = 0; st < ST; st++) {
        const float* p = xrow + quad * 8 + 32 * st;
        float4 a = *(const float4*)p;
        float4 bq = *(const float4*)(p + 4);
        float h[8] = {a.x, a.y, a.z, a.w, bq.x, bq.y, bq.z, bq.w};
        short8 ah, al;
#pragma unroll
        for (int j = 0; j < 8; j++) {
            float v = h[j];
            ushort_t hb = f2us_tr(v);
            float lo = v - us2f(hb);
            ah[j] = (short)hb;
            al[j] = (short)f2us_tr(lo);
        }
        Ahi[st] = ah; Alo[st] = al;
    }

    const float* bs_[4] = {b0, b1, b2, b3};

#pragma unroll
    for (int mat = 0; mat < 4; mat++) {
        const ushort_t* Bh = Whi + (mat * 256 + nsl * 64) * IN;
        const ushort_t* Bl = Wlo + (mat * 256 + nsl * 64) * IN;
        fx4 G[4];
#pragma unroll
        for (int tile = 0; tile < 4; tile++) {
            float bc = bs_[mat][nsl * 64 + tile * 16 + nl];
            G[tile] = (fx4){bc, bc, bc, bc};
        }
#pragma unroll
        for (int st = 0; st < ST; st++) {
            int kx = (quad * 8 + 32 * st) ^ (nl * 8);
            short8 bh8[4], bl8[4];
#pragma unroll
            for (int tile = 0; tile < 4; tile++) {
                int off = (tile * 16 + nl) * IN + kx;
                bh8[tile] = *(const short8*)(Bh + off);
                bl8[tile] = *(const short8*)(Bl + off);
            }
#pragma unroll
            for (int tile = 0; tile < 4; tile++) {
                G[tile] = __builtin_amdgcn_mfma_f32_16x16x32_bf16(Ahi[st], bh8[tile], G[tile], 0, 0, 0);
                G[tile] = __builtin_amdgcn_mfma_f32_16x16x32_bf16(Alo[st], bh8[tile], G[tile], 0, 0, 0);
                G[tile] = __builtin_amdgcn_mfma_f32_16x16x32_bf16(Ahi[st], bl8[tile], G[tile], 0, 0, 0);
            }
        }
        int row0 = m0 + wv * 16 + quad * 4;
        if (mat == 0 || mat == 3) {
            float* om = (mat == 0) ? q : skipo;
#pragma unroll
            for (int tile = 0; tile < 4; tile++)
#pragma unroll
                for (int r = 0; r < 4; r++)
                    om[(row0 + r) * HD + nsl * 64 + tile * 16 + nl] = G[tile][r];
        } else if (mat == 1) {
#pragma unroll
            for (int tile = 0; tile < 4; tile++) {
                int col = nsl * 64 + tile * 16 + nl;
#pragma unroll
                for (int r = 0; r < 4; r++) {
                    float gv = G[tile][r];
                    ushort_t hb = f2us_tr(gv);
                    khi[(row0 + r) * HD + col] = hb;
                    klo[(row0 + r) * HD + col] = f2us_tr(gv - us2f(hb));
                }
            }
        } else {
            int bb = row0 >> 7;
            int s0 = row0 & 127;
#pragma unroll
            for (int tile = 0; tile < 4; tile++) {
                int col = nsl * 64 + tile * 16 + nl;
                int dg = bb * 256 + col;
                ushort4 h4, l4;
                float g0 = G[tile][0], g1 = G[tile][1], g2 = G[tile][2], g3 = G[tile][3];
                ushort_t h0 = f2us_tr(g0), h1 = f2us_tr(g1), h2 = f2us_tr(g2), h3 = f2us_tr(g3);
                h4.x = h0; h4.y = h1; h4.z = h2; h4.w = h3;
                l4.x = f2us_tr(g0 - us2f(h0));
                l4.y = f2us_tr(g1 - us2f(h1));
                l4.z = f2us_tr(g2 - us2f(h2));
                l4.w = f2us_tr(g3 - us2f(h3));
                *(ushort4*)&vThi[dg * NN + s0] = h4;
                *(ushort4*)&vTlo[dg * NN + s0] = l4;
            }
        }
    }
}

// ---------------- K6: attention via MFMA — R10 version verbatim -----------
__global__ void __launch_bounds__(64) k_attn_mfma(
    const float* qb, const ushort_t* khi, const ushort_t* klo,
    const ushort_t* vThi, const ushort_t* vTlo,
    const float* adjvT, const float* We, const float* skip, float* xout)
{
    __shared__ float aL[16][132];     // alpha C->A round-trip (8.4 KB)
    __shared__ float qeL[16];

    int blk = blockIdx.x;             // 1024 = 32b*4h*8tt
    int b  = blk >> 5;
    int h  = (blk >> 3) & 3;
    int tt = blk & 7;
    int t0 = tt * 16;
    int lane = threadIdx.x;
    int nl = lane & 15;
    int quad = lane >> 4;

    short8 Qhi[2], Qlo[2];
    float qe = 0.f;
#pragma unroll
    for (int ks = 0; ks < 2; ks++) {
        const float* p = qb + (b * NN + t0 + nl) * HD + h * DHEAD + quad * 8 + 32 * ks;
        const float* wp = We + h * DHEAD + quad * 8 + 32 * ks;
        float4 a0 = *(const float4*)p;
        float4 a1 = *(const float4*)(p + 4);
        float4 w0 = *(const float4*)wp;
        float4 w1 = *(const float4*)(wp + 4);
        float hv[8] = {a0.x, a0.y, a0.z, a0.w, a1.x, a1.y, a1.z, a1.w};
        float wv8[8] = {w0.x, w0.y, w0.z, w0.w, w1.x, w1.y, w1.z, w1.w};
        short8 ah, al;
#pragma unroll
        for (int j = 0; j < 8; j++) {
            float v = hv[j];
            ushort_t hb = f2us_tr(v);
            ah[j] = (short)hb;
            al[j] = (short)f2us_tr(v - us2f(hb));
            qe += v * wv8[j];
        }
        Qhi[ks] = ah; Qlo[ks] = al;
    }
    qe += __shfl_xor(qe, 16);
    qe += __shfl_xor(qe, 32);
    if (lane < 16) qeL[lane] = qe;
    __syncthreads();
    float qe_r[4];
#pragma unroll
    for (int r = 0; r < 4; r++) qe_r[r] = qeL[quad * 4 + r];
    float we_d[4];
#pragma unroll
    for (int nt = 0; nt < 4; nt++) we_d[nt] = We[h * DHEAD + nt * 16 + nl];

    fx4 S[8];
#pragma unroll
    for (int st = 0; st < 8; st++) S[st] = (fx4){0.f, 0.f, 0.f, 0.f};
#pragma unroll
    for (int ks = 0; ks < 2; ks++) {
#pragma unroll
        for (int st = 0; st < 8; st++) {
            long off = (long)(b * NN + st * 16 + nl) * HD + h * DHEAD + quad * 8 + 32 * ks;
            short8 bh8 = *(const short8*)(khi + off);
            short8 bl8 = *(const short8*)(klo + off);
            S[st] = __builtin_amdgcn_mfma_f32_16x16x32_bf16(Qhi[ks], bh8, S[st], 0, 0, 0);
            S[st] = __builtin_amdgcn_mfma_f32_16x16x32_bf16(Qlo[ks], bh8, S[st], 0, 0, 0);
            S[st] = __builtin_amdgcn_mfma_f32_16x16x32_bf16(Qhi[ks], bl8, S[st], 0, 0, 0);
        }
    }

    float av[8][4];
#pragma unroll
    for (int st = 0; st < 8; st++)
#pragma unroll
        for (int r = 0; r < 4; r++)
            av[st][r] = adjvT[(b * NN + t0 + quad * 4 + r) * NN + st * 16 + nl];
#pragma unroll
    for (int st = 0; st < 8; st++)
#pragma unroll
        for (int r = 0; r < 4; r++) {
            float a = av[st][r];
            S[st][r] = (a != 0.f) ? (S[st][r] + a * qe_r[r]) * 0.125f : -1e30f;
        }

    float mx[4], den[4], beta[4];
#pragma unroll
    for (int r = 0; r < 4; r++) {
        float m = S[0][r];
#pragma unroll
        for (int st = 1; st < 8; st++) m = fmaxf(m, S[st][r]);
#pragma unroll
        for (int mm = 1; mm < 16; mm <<= 1) m = fmaxf(m, __shfl_xor(m, mm));
        mx[r] = m;
        den[r] = 0.f;
    }
#pragma unroll
    for (int st = 0; st < 8; st++)
#pragma unroll
        for (int r = 0; r < 4; r++) {
            float e = (av[st][r] != 0.f) ? __expf(S[st][r] - mx[r]) : 0.f;
            S[st][r] = e;
            den[r] += e;
        }
#pragma unroll
    for (int r = 0; r < 4; r++) {
#pragma unroll
        for (int mm = 1; mm < 16; mm <<= 1) den[r] += __shfl_xor(den[r], mm);
        den[r] = 1.f / fmaxf(den[r], 1e-16f);
        beta[r] = 0.f;
    }
#pragma unroll
    for (int st = 0; st < 8; st++)
#pragma unroll
        for (int r = 0; r < 4; r++) {
            float al = S[st][r] * den[r];
            S[st][r] = al;
            beta[r] += al * av[st][r];
        }
#pragma unroll
    for (int r = 0; r < 4; r++)
#pragma unroll
        for (int mm = 1; mm < 16; mm <<= 1) beta[r] += __shfl_xor(beta[r], mm);

#pragma unroll
    for (int st = 0; st < 8; st++)
#pragma unroll
        for (int r = 0; r < 4; r++)
            aL[quad * 4 + r][st * 16 + nl] = S[st][r];
    __syncthreads();
    short8 Ah[4];
#pragma unroll
    for (int ks = 0; ks < 4; ks++) {
        const float* p = &aL[nl][quad * 8 + 32 * ks];
        float4 a0 = *(const float4*)p;
        float4 a1 = *(const float4*)(p + 4);
        float hv[8] = {a0.x, a0.y, a0.z, a0.w, a1.x, a1.y, a1.z, a1.w};
        short8 ah;
#pragma unroll
        for (int j = 0; j < 8; j++) ah[j] = (short)f2us_tr(hv[j]);
        Ah[ks] = ah;
    }

    fx4 G[4];
#pragma unroll
    for (int nt = 0; nt < 4; nt++) {
        fx4 g;
#pragma unroll
        for (int r = 0; r < 4; r++) g[r] = beta[r] * we_d[nt];
        G[nt] = g;
    }
#pragma unroll
    for (int ks = 0; ks < 4; ks++) {
#pragma unroll
        for (int nt = 0; nt < 4; nt++) {
            long dg = (long)(b * 256 + h * DHEAD + nt * 16 + nl);
            const short8 vh = *(const short8*)(vThi + dg * NN + quad * 8 + 32 * ks);
            const short8 vl = *(const short8*)(vTlo + dg * NN + quad * 8 + 32 * ks);
            G[nt] = __builtin_amdgcn_mfma_f32_16x16x32_bf16(Ah[ks], vh, G[nt], 0, 0, 0);
            G[nt] = __builtin_amdgcn_mfma_f32_16x16x32_bf16(Ah[ks], vl, G[nt], 0, 0, 0);
        }
    }

#pragma unroll
    for (int nt = 0; nt < 4; nt++)
#pragma unroll
        for (int r = 0; r < 4; r++) {
            int gi = (b * NN + t0 + quad * 4 + r) * HD + h * DHEAD + nt * 16 + nl;
            xout[gi] = fmaxf(G[nt][r] + skip[gi], 0.f);
        }
}

// ---------------- K8: gather agent rows -> f32 out ----------------
__global__ void k_gather(const float* x2, const int* agent, float* out) {
    int b = blockIdx.x;
    int c = threadIdx.x;
    out[b * HD + c] = x2[(b * NN + agent[b]) * HD + c];
}

// ---------------- launch — R10 layout/sequence ----------------
extern "C" void kernel_launch(void* const* d_in, const int* in_sizes, int n_in,
                              void* d_out, int out_size, void* d_ws, size_t ws_size,
                              hipStream_t stream) {
    float* out = (float*)d_out;
    (void)hipGetLastError();

    bool ok = (n_in == 31) && in_sizes[0] == BB * NN * FF && in_sizes[2] == BB * NN * NN
              && in_sizes[5] == (FF + EE + 1) * HH && in_sizes[13] == HH * HD
              && in_sizes[22] == HD * HD && out_size == BB * HD;
    if (!ok) { k_sent<<<32, 256, 0, stream>>>(out, -30000.f); return; }

    const size_t WS_NEED = (size_t)8912896 * 4;
    if (ws_size < WS_NEED) { k_sent<<<32, 256, 0, stream>>>(out, -20000.f); return; }

    const float* nf    = (const float*)d_in[0];
    const int*   et    = (const int*)d_in[1];
    const float* adj   = (const float*)d_in[2];
    const int*   agent = (const int*)d_in[3];
    const float* emb   = (const float*)d_in[4];
    const float* W1    = (const float*)d_in[5];
    const float* b1    = (const float*)d_in[6];
    const float* g1    = (const float*)d_in[7];
    const float* be1   = (const float*)d_in[8];
    const float* Wh    = (const float*)d_in[9];
    const float* bh    = (const float*)d_in[10];
    const float* gh    = (const float*)d_in[11];
    const float* beh   = (const float*)d_in[12];
    const float* Wq1   = (const float*)d_in[13];
    const float* bq1   = (const float*)d_in[14];
    const float* Wk1   = (const float*)d_in[15];
    const float* bk1   = (const float*)d_in[16];
    const float* Wv1   = (const float*)d_in[17];
    const float* bv1   = (const float*)d_in[18];
    const float* We1   = (const float*)d_in[19];
    const float* Ws1   = (const float*)d_in[20];
    const float* bs1   = (const float*)d_in[21];
    const float* Wq2   = (const float*)d_in[22];
    const float* bq2   = (const float*)d_in[23];
    const float* Wk2   = (const float*)d_in[24];
    const float* bk2   = (const float*)d_in[25];
    const float* Wv2   = (const float*)d_in[26];
    const float* bv2   = (const float*)d_in[27];
    const float* We2   = (const float*)d_in[28];
    const float* Ws2   = (const float*)d_in[29];
    const float* bs2   = (const float*)d_in[30];

    float* ws   = (float*)d_ws;
    float* adjv = ws;                              // 524288 f
    float* base = adjv + BB * NN * NN;             // 524288 f
    float* x0   = base + BB * NN * HH;             // 524288 f
    float* q    = x0 + BB * NN * HH;               // 1048576 f
    float* kreg = q + BB * NN * HD;                // -> khi/klo
    float* vreg = kreg + BB * NN * HD;             // -> vThi/vTlo
    float* skip = vreg + BB * NN * HD;
    float* areg = skip + BB * NN * HD;             // weight planes + adjvT
    float* x1   = areg + BB * NN * HD;
    float* x2   = x1 + BB * NN * HD;

    ushort_t* BhiG = (ushort_t*)q;
    ushort_t* BloG = BhiG + HH * HH;
    float*    W1sW = q + 16384;
    float*    cbW  = q + 16512;

    ushort_t* khi  = (ushort_t*)kreg;
    ushort_t* klo  = khi + BB * NN * HD;
    ushort_t* vThi = (ushort_t*)vreg;
    ushort_t* vTlo = vThi + BB * NN * HD;

    ushort_t* WhA = (ushort_t*)areg;
    ushort_t* WlA = WhA + 4 * 256 * HH;
    ushort_t* WhB = WlA + 4 * 256 * HH;
    ushort_t* WlB = WhB + 4 * 256 * HD;
    float* adjvT  = areg + 393216;

    int fail = 0;
    hipError_t e;
#define CHK(stage) do { e = hipGetLastError(); if (e != hipSuccess && fail == 0) fail = (stage); } while (0)

    k_adjv<<<BB, 256, 0, stream>>>(adj, adjv, adjvT);                                CHK(1);
    k_base<<<BB * NN, HH, 0, stream>>>(nf, et, emb, W1, b1, base);                   CHK(2);
    k_zero<<<BB * NN * HH / 256, 256, 0, stream>>>(x0);                              CHK(3);
    k_prep<<<HH, 64, 0, stream>>>(Wh, g1, be1, bh, BhiG, BloG, W1sW, cbW);           CHK(4);
    k_prepw<<<1024, 64, 0, stream>>>(Wq1, Wk1, Wv1, Ws1, HH, WhA, WlA);              CHK(5);
    k_prepw<<<1024, 64, 0, stream>>>(Wq2, Wk2, Wv2, Ws2, HD, WhB, WlB);              CHK(6);
    k_econv_mfma<<<512, 256, 0, stream>>>(adjv, base, W1, BhiG, BloG, W1sW, cbW,
                                          gh, beh, x0);                              CHK(7);

    k_qkvs_mfma<HH><<<256, 256, 0, stream>>>(x0, WhA, WlA, bq1, bk1, bv1, bs1,
                                             q, skip, khi, klo, vThi, vTlo);         CHK(8);
    k_attn_mfma<<<1024, 64, 0, stream>>>(q, khi, klo, vThi, vTlo, adjvT, We1,
                                         skip, x1);                                  CHK(9);

    k_qkvs_mfma<HD><<<256, 256, 0, stream>>>(x1, WhB, WlB, bq2, bk2, bv2, bs2,
                                             q, skip, khi, klo, vThi, vTlo);         CHK(10);
    k_attn_mfma<<<1024, 64, 0, stream>>>(q, khi, klo, vThi, vTlo, adjvT, We2,
                                         skip, x2);                                  CHK(11);

    k_gather<<<BB, HD, 0, stream>>>(x2, agent, out);                                 CHK(12);
#undef CHK

    if (fail != 0)
        k_sent<<<32, 256, 0, stream>>>(out, -(1000.f + 500.f * (float)fail));
}

// Round 13
// 367.253 us; speedup vs baseline: 1.0078x; 1.0078x over previous
//
#include <hip/hip_runtime.h>
#include <hip/hip_bf16.h>

typedef __hip_bfloat16 bf16;
typedef unsigned short ushort_t;
typedef __attribute__((ext_vector_type(8))) short short8;
typedef __attribute__((ext_vector_type(4))) float fx4;

#define BB 32
#define NN 128
#define FF 9
#define EE 8
#define HH 128
#define HD 256
#define NHEAD 4
#define DHEAD 64

__device__ __forceinline__ float us2f(ushort_t u) {
    return __uint_as_float(((unsigned int)u) << 16);
}
__device__ __forceinline__ ushort_t f2us_tr(float f) {
    return (ushort_t)(__float_as_uint(f) >> 16);
}

__global__ void TransformerConvNet_85315230367963_kernel() {}

__global__ void k_sent(float* out, float val) {
    out[blockIdx.x * 256 + threadIdx.x] = val;
}

// ---------------- K1: adjv + adjvT (masked) — R10 version ----------------
__global__ void k_adjv(const float* adj, float* adjv, float* adjvT) {
    int b = blockIdx.x;            // 32
    const float* src = adj + b * NN * NN;
    float* d1 = adjv + b * NN * NN;
    float* d2 = adjvT + b * NN * NN;
    for (int i = threadIdx.x; i < NN * NN; i += 256) {
        float a = src[i];
        d1[i] = (a > 0.f && a < 1.0f) ? a : 0.f;
    }
    for (int i = threadIdx.x; i < NN * NN; i += 256) {
        int t = i >> 7, s = i & 127;
        float a = src[s * NN + t];
        d2[i] = (a > 0.f && a < 1.0f) ? a : 0.f;   // adjvT[t][s]
    }
}

// ---------------- K2: base = src @ W1[:17] + b1; also zeroes x0 -----------
__global__ void k_base(const float* nf, const int* et, const float* emb,
                       const float* W1, const float* b1, float* base, float* x0) {
    int bs = blockIdx.x;
    int c = threadIdx.x;
    x0[bs * HH + c] = 0.f;          // grid exactly covers x0 (4096*128)
    int ty = et[bs];
    float acc = b1[c];
    for (int f = 0; f < FF; f++)
        acc += nf[bs * FF + f] * W1[f * HH + c];
    for (int e = 0; e < EE; e++)
        acc += emb[ty * EE + e] * W1[(FF + e) * HH + c];
    base[bs * HH + c] = acc;
}

// ---------------- K_prep: Wh' = g1*Wh split bf16 hi/lo, swizzled ----------
__global__ void k_prep(const float* Wh, const float* g1, const float* be1,
                       const float* bh, ushort_t* BhiG, ushort_t* BloG,
                       float* W1s, float* cbv) {
    int n = blockIdx.x;      // 0..127
    int t = threadIdx.x;     // 0..63
    int sw = 8 * (n & 15);
    float s1 = 0.f, s2 = 0.f;
    for (int kk = 0; kk < 2; kk++) {
        int k = t + kk * 64;
        float w = Wh[k * HH + n];
        float wp = g1[k] * w;
        ushort_t hb = f2us_tr(wp);
        float lo = wp - us2f(hb);
        BhiG[n * HH + (k ^ sw)] = hb;
        BloG[n * HH + (k ^ sw)] = f2us_tr(lo);
        s1 += wp;
        s2 += be1[k] * w;
    }
    for (int m = 1; m < 64; m <<= 1) {
        s1 += __shfl_xor(s1, m);
        s2 += __shfl_xor(s2, m);
    }
    if (t == 0) { W1s[n] = s1; cbv[n] = s2 + bh[n]; }
}

// ---------------- K_prepw: split 4 qkvs weight mats into bf16 hi/lo -------
__global__ void k_prepw(const float* W0, const float* W1p, const float* W2p,
                        const float* W3p, int IN, ushort_t* Whi, ushort_t* Wlo) {
    int blk = blockIdx.x;             // 4*256
    int mat = blk >> 8, n = blk & 255;
    const float* W = (mat == 0) ? W0 : (mat == 1) ? W1p : (mat == 2) ? W2p : W3p;
    ushort_t* hi = Whi + mat * 256 * IN;
    ushort_t* lo = Wlo + mat * 256 * IN;
    int sw = 8 * (n & 15);
    for (int k = threadIdx.x; k < IN; k += 64) {
        float w = W[k * HD + n];
        ushort_t hb = f2us_tr(w);
        float l = w - us2f(hb);
        hi[n * IN + (k ^ sw)] = hb;
        lo[n * IN + (k ^ sw)] = f2us_tr(l);
    }
}

// ---------------- K3: embed conv MFMA — R12 version verbatim --------------
__global__ void __launch_bounds__(256) k_econv_mfma(
    const float* adjv, const float* base, const float* W1,
    const ushort_t* BhiG, const ushort_t* BloG,
    const float* W1s, const float* cbv,
    const float* ghp, const float* behp, float* x0)
{
    __shared__ __align__(16) ushort_t Bhi[HH * HH];
    __shared__ __align__(16) ushort_t Blo[HH * HH];

    int blk = blockIdx.x;
    int b  = blk >> 4;
    int tt = (blk >> 1) & 7;
    int sh = blk & 1;
    int t0 = tt * 16;
    int tid = threadIdx.x;
    int wv  = tid >> 6;
    int lane = tid & 63;
    int nl = lane & 15;
    int quad = lane >> 4;

    {
        const uint4* srcH = (const uint4*)BhiG;
        const uint4* srcL = (const uint4*)BloG;
        uint4* dstH = (uint4*)Bhi;
        uint4* dstL = (uint4*)Blo;
        for (int i = tid; i < HH * HH / 8; i += 256) {
            dstH[i] = srcH[i];
            dstL[i] = srcL[i];
        }
    }

    float W1s_r[8], cb_r[8], gh_r[8], beh_r[8];
#pragma unroll
    for (int tile = 0; tile < 8; tile++) {
        int c = tile * 16 + nl;
        W1s_r[tile] = W1s[c];
        cb_r[tile]  = cbv[c];
        gh_r[tile]  = ghp[c];
        beh_r[tile] = behp[c];
    }
    float w17v[4][8];
#pragma unroll
    for (int st = 0; st < 4; st++) {
        const float* p = W1 + 17 * HH + quad * 8 + 32 * st;
        float4 a = *(const float4*)p;
        float4 bq = *(const float4*)(p + 4);
        w17v[st][0] = a.x;  w17v[st][1] = a.y;  w17v[st][2] = a.z;  w17v[st][3] = a.w;
        w17v[st][4] = bq.x; w17v[st][5] = bq.y; w17v[st][6] = bq.z; w17v[st][7] = bq.w;
    }

    fx4 xacc[8];
#pragma unroll
    for (int tile = 0; tile < 8; tile++) xacc[tile] = (fx4){0.f, 0.f, 0.f, 0.f};

    __syncthreads();

    int sBase = sh * 64 + wv * 16;
    float av_c = adjv[(b * NN + sBase) * NN + t0 + nl];   // rolling prefetch

    for (int i = 0; i < 16; i++) {
        int s = sBase + i;
        float av_n = (i < 15) ? adjv[(b * NN + s + 1) * NN + t0 + nl] : 0.f;
        const float* brow = base + (b * NN + s) * HH;
        float avv = av_c;

        short8 Ahi[4], Alo[4];
        float sm = 0.f, s2 = 0.f;
#pragma unroll
        for (int st = 0; st < 4; st++) {
            const float* p = brow + quad * 8 + 32 * st;
            float4 b0 = *(const float4*)p;
            float4 b1q = *(const float4*)(p + 4);
            float h[8] = {b0.x, b0.y, b0.z, b0.w, b1q.x, b1q.y, b1q.z, b1q.w};
            short8 ah, al;
#pragma unroll
            for (int j = 0; j < 8; j++) {
                float v = fmaxf(h[j] + avv * w17v[st][j], 0.f);
                sm += v; s2 += v * v;
                ushort_t hb = f2us_tr(v);
                float lo = v - us2f(hb);
                ah[j] = (short)hb;
                al[j] = (short)f2us_tr(lo);
            }
            Ahi[st] = ah; Alo[st] = al;
        }
        sm += __shfl_xor(sm, 16); sm += __shfl_xor(sm, 32);
        s2 += __shfl_xor(s2, 16); s2 += __shfl_xor(s2, 32);
        float m1 = sm * (1.f / 128.f);
        float r1 = rsqrtf(s2 * (1.f / 128.f) - m1 * m1 + 1e-5f);

        float m1d[4], r1d[4], avd[4];
#pragma unroll
        for (int r = 0; r < 4; r++) {
            int src = quad * 4 + r;
            m1d[r] = __shfl(m1, src);
            r1d[r] = __shfl(r1, src);
            avd[r] = __shfl(avv, src);
        }

        fx4 G[8];
#pragma unroll
        for (int tile = 0; tile < 8; tile++) G[tile] = (fx4){0.f, 0.f, 0.f, 0.f};
#pragma unroll
        for (int st = 0; st < 4; st++) {
            int kx = (quad * 8 + 32 * st) ^ (nl * 8);
#pragma unroll
            for (int g = 0; g < 2; g++) {
                short8 bh8[4], bl8[4];
#pragma unroll
                for (int t4 = 0; t4 < 4; t4++) {
                    int off = ((g * 4 + t4) * 16 + nl) * HH + kx;
                    bh8[t4] = *(const short8*)(&Bhi[off]);
                    bl8[t4] = *(const short8*)(&Blo[off]);
                }
#pragma unroll
                for (int t4 = 0; t4 < 4; t4++) {
                    int tile = g * 4 + t4;
                    G[tile] = __builtin_amdgcn_mfma_f32_16x16x32_bf16(Ahi[st], bh8[t4], G[tile], 0, 0, 0);
                    G[tile] = __builtin_amdgcn_mfma_f32_16x16x32_bf16(Alo[st], bh8[t4], G[tile], 0, 0, 0);
                    G[tile] = __builtin_amdgcn_mfma_f32_16x16x32_bf16(Ahi[st], bl8[t4], G[tile], 0, 0, 0);
                }
            }
        }

        float sm2[4] = {0.f, 0.f, 0.f, 0.f}, ss2[4] = {0.f, 0.f, 0.f, 0.f};
#pragma unroll
        for (int tile = 0; tile < 8; tile++) {
#pragma unroll
            for (int r = 0; r < 4; r++) {
                float h2 = fmaxf(r1d[r] * (G[tile][r] - m1d[r] * W1s_r[tile]) + cb_r[tile], 0.f);
                G[tile][r] = h2;
                sm2[r] += h2; ss2[r] += h2 * h2;
            }
        }
#pragma unroll
        for (int r = 0; r < 4; r++) {
#pragma unroll
            for (int m = 1; m < 16; m <<= 1) {
                sm2[r] += __shfl_xor(sm2[r], m);
                ss2[r] += __shfl_xor(ss2[r], m);
            }
        }
        float mean2[4], r2v[4];
#pragma unroll
        for (int r = 0; r < 4; r++) {
            mean2[r] = sm2[r] * (1.f / 128.f);
            float var = ss2[r] * (1.f / 128.f) - mean2[r] * mean2[r];
            r2v[r] = rsqrtf(var + 1e-5f);
        }
#pragma unroll
        for (int tile = 0; tile < 8; tile++) {
#pragma unroll
            for (int r = 0; r < 4; r++) {
                float h2n = (G[tile][r] - mean2[r]) * r2v[r] * gh_r[tile] + beh_r[tile];
                if (avd[r] != 0.f) xacc[tile][r] += h2n;
            }
        }
        av_c = av_n;
    }

#pragma unroll
    for (int tile = 0; tile < 8; tile++)
#pragma unroll
        for (int r = 0; r < 4; r++)
            atomicAdd(&x0[(b * NN + t0 + quad * 4 + r) * HH + tile * 16 + nl], xacc[tile][r]);
}

// ---------------- K5: qkvs via MFMA — R12 version verbatim ----------------
template <int IN>
__global__ void __launch_bounds__(256) k_qkvs_mfma(
    const float* x, const ushort_t* Whi, const ushort_t* Wlo,
    const float* b0, const float* b1, const float* b2, const float* b3,
    float* q, float* skipo,
    ushort_t* khi, ushort_t* klo, ushort_t* vThi, ushort_t* vTlo)
{
    const int ST = IN / 32;
    int blk = blockIdx.x;
    int m0 = (blk >> 2) * 64;
    int nsl = blk & 3;
    int tid = threadIdx.x;
    int wv = tid >> 6;
    int lane = tid & 63;
    int nl = lane & 15;
    int quad = lane >> 4;
    int row = m0 + wv * 16 + nl;

    short8 Ahi[ST], Alo[ST];
    const float* xrow = x + (long)row * IN;
#pragma unroll
    for (int st = 0; st < ST; st++) {
        const float* p = xrow + quad * 8 + 32 * st;
        float4 a = *(const float4*)p;
        float4 bq = *(const float4*)(p + 4);
        float h[8] = {a.x, a.y, a.z, a.w, bq.x, bq.y, bq.z, bq.w};
        short8 ah, al;
#pragma unroll
        for (int j = 0; j < 8; j++) {
            float v = h[j];
            ushort_t hb = f2us_tr(v);
            float lo = v - us2f(hb);
            ah[j] = (short)hb;
            al[j] = (short)f2us_tr(lo);
        }
        Ahi[st] = ah; Alo[st] = al;
    }

    const float* bs_[4] = {b0, b1, b2, b3};

#pragma unroll
    for (int mat = 0; mat < 4; mat++) {
        const ushort_t* Bh = Whi + (mat * 256 + nsl * 64) * IN;
        const ushort_t* Bl = Wlo + (mat * 256 + nsl * 64) * IN;
        fx4 G[4];
#pragma unroll
        for (int tile = 0; tile < 4; tile++) {
            float bc = bs_[mat][nsl * 64 + tile * 16 + nl];
            G[tile] = (fx4){bc, bc, bc, bc};
        }
#pragma unroll
        for (int st = 0; st < ST; st++) {
            int kx = (quad * 8 + 32 * st) ^ (nl * 8);
            short8 bh8[4], bl8[4];
#pragma unroll
            for (int tile = 0; tile < 4; tile++) {
                int off = (tile * 16 + nl) * IN + kx;
                bh8[tile] = *(const short8*)(Bh + off);
                bl8[tile] = *(const short8*)(Bl + off);
            }
#pragma unroll
            for (int tile = 0; tile < 4; tile++) {
                G[tile] = __builtin_amdgcn_mfma_f32_16x16x32_bf16(Ahi[st], bh8[tile], G[tile], 0, 0, 0);
                G[tile] = __builtin_amdgcn_mfma_f32_16x16x32_bf16(Alo[st], bh8[tile], G[tile], 0, 0, 0);
                G[tile] = __builtin_amdgcn_mfma_f32_16x16x32_bf16(Ahi[st], bl8[tile], G[tile], 0, 0, 0);
            }
        }
        int row0 = m0 + wv * 16 + quad * 4;
        if (mat == 0 || mat == 3) {
            float* om = (mat == 0) ? q : skipo;
#pragma unroll
            for (int tile = 0; tile < 4; tile++)
#pragma unroll
                for (int r = 0; r < 4; r++)
                    om[(row0 + r) * HD + nsl * 64 + tile * 16 + nl] = G[tile][r];
        } else if (mat == 1) {
#pragma unroll
            for (int tile = 0; tile < 4; tile++) {
                int col = nsl * 64 + tile * 16 + nl;
#pragma unroll
                for (int r = 0; r < 4; r++) {
                    float gv = G[tile][r];
                    ushort_t hb = f2us_tr(gv);
                    khi[(row0 + r) * HD + col] = hb;
                    klo[(row0 + r) * HD + col] = f2us_tr(gv - us2f(hb));
                }
            }
        } else {
            int bb = row0 >> 7;
            int s0 = row0 & 127;
#pragma unroll
            for (int tile = 0; tile < 4; tile++) {
                int col = nsl * 64 + tile * 16 + nl;
                int dg = bb * 256 + col;
                ushort4 h4, l4;
                float g0 = G[tile][0], g1 = G[tile][1], g2 = G[tile][2], g3 = G[tile][3];
                ushort_t h0 = f2us_tr(g0), h1 = f2us_tr(g1), h2 = f2us_tr(g2), h3 = f2us_tr(g3);
                h4.x = h0; h4.y = h1; h4.z = h2; h4.w = h3;
                l4.x = f2us_tr(g0 - us2f(h0));
                l4.y = f2us_tr(g1 - us2f(h1));
                l4.z = f2us_tr(g2 - us2f(h2));
                l4.w = f2us_tr(g3 - us2f(h3));
                *(ushort4*)&vThi[dg * NN + s0] = h4;
                *(ushort4*)&vTlo[dg * NN + s0] = l4;
            }
        }
    }
}

// ---------------- K6: attention MFMA — preloaded frags + qe-shuffle -------
// (the single R11 suspect reintroduced this round; arithmetic identical)
__global__ void __launch_bounds__(64) k_attn_mfma(
    const float* qb, const ushort_t* khi, const ushort_t* klo,
    const ushort_t* vThi, const ushort_t* vTlo,
    const float* adjvT, const float* We, const float* skip, float* xout)
{
    __shared__ float aL[16][132];     // alpha C->A round-trip

    int blk = blockIdx.x;             // 1024 = 32b*4h*8tt
    int b  = blk >> 5;
    int h  = (blk >> 3) & 3;
    int tt = blk & 7;
    int t0 = tt * 16;
    int lane = threadIdx.x;
    int nl = lane & 15;
    int quad = lane >> 4;

    // Q frags + qe via shuffles (no LDS/barrier)
    short8 Qhi[2], Qlo[2];
    float qe = 0.f;
#pragma unroll
    for (int ks = 0; ks < 2; ks++) {
        const float* p = qb + (b * NN + t0 + nl) * HD + h * DHEAD + quad * 8 + 32 * ks;
        const float* wp = We + h * DHEAD + quad * 8 + 32 * ks;
        float4 a0 = *(const float4*)p;
        float4 a1 = *(const float4*)(p + 4);
        float4 w0 = *(const float4*)wp;
        float4 w1 = *(const float4*)(wp + 4);
        float hv[8] = {a0.x, a0.y, a0.z, a0.w, a1.x, a1.y, a1.z, a1.w};
        float wv8[8] = {w0.x, w0.y, w0.z, w0.w, w1.x, w1.y, w1.z, w1.w};
        short8 ah, al;
#pragma unroll
        for (int j = 0; j < 8; j++) {
            float v = hv[j];
            ushort_t hb = f2us_tr(v);
            ah[j] = (short)hb;
            al[j] = (short)f2us_tr(v - us2f(hb));
            qe += v * wv8[j];
        }
        Qhi[ks] = ah; Qlo[ks] = al;
    }
    qe += __shfl_xor(qe, 16);
    qe += __shfl_xor(qe, 32);          // lane i now holds qe for t = i&15
    float qe_r[4];
#pragma unroll
    for (int r = 0; r < 4; r++) qe_r[r] = __shfl(qe, quad * 4 + r);

    // preload ALL K frags (32) + adjvT (32) before the 48 QK MFMAs
    short8 Kh[16], Kl[16];
#pragma unroll
    for (int ks = 0; ks < 2; ks++)
#pragma unroll
        for (int st = 0; st < 8; st++) {
            long off = (long)(b * NN + st * 16 + nl) * HD + h * DHEAD + quad * 8 + 32 * ks;
            Kh[ks * 8 + st] = *(const short8*)(khi + off);
            Kl[ks * 8 + st] = *(const short8*)(klo + off);
        }
    float av[8][4];
#pragma unroll
    for (int st = 0; st < 8; st++)
#pragma unroll
        for (int r = 0; r < 4; r++)
            av[st][r] = adjvT[(b * NN + t0 + quad * 4 + r) * NN + st * 16 + nl];

    fx4 S[8];
#pragma unroll
    for (int st = 0; st < 8; st++) S[st] = (fx4){0.f, 0.f, 0.f, 0.f};
#pragma unroll
    for (int ks = 0; ks < 2; ks++)
#pragma unroll
        for (int st = 0; st < 8; st++) {
            S[st] = __builtin_amdgcn_mfma_f32_16x16x32_bf16(Qhi[ks], Kh[ks * 8 + st], S[st], 0, 0, 0);
            S[st] = __builtin_amdgcn_mfma_f32_16x16x32_bf16(Qlo[ks], Kh[ks * 8 + st], S[st], 0, 0, 0);
            S[st] = __builtin_amdgcn_mfma_f32_16x16x32_bf16(Qhi[ks], Kl[ks * 8 + st], S[st], 0, 0, 0);
        }

#pragma unroll
    for (int st = 0; st < 8; st++)
#pragma unroll
        for (int r = 0; r < 4; r++) {
            float a = av[st][r];
            S[st][r] = (a != 0.f) ? (S[st][r] + a * qe_r[r]) * 0.125f : -1e30f;
        }

    float mx[4], den[4], beta[4];
#pragma unroll
    for (int r = 0; r < 4; r++) {
        float m = S[0][r];
#pragma unroll
        for (int st = 1; st < 8; st++) m = fmaxf(m, S[st][r]);
#pragma unroll
        for (int mm = 1; mm < 16; mm <<= 1) m = fmaxf(m, __shfl_xor(m, mm));
        mx[r] = m;
        den[r] = 0.f;
    }
#pragma unroll
    for (int st = 0; st < 8; st++)
#pragma unroll
        for (int r = 0; r < 4; r++) {
            float e = (av[st][r] != 0.f) ? __expf(S[st][r] - mx[r]) : 0.f;
            S[st][r] = e;
            den[r] += e;
        }
#pragma unroll
    for (int r = 0; r < 4; r++) {
#pragma unroll
        for (int mm = 1; mm < 16; mm <<= 1) den[r] += __shfl_xor(den[r], mm);
        den[r] = 1.f / fmaxf(den[r], 1e-16f);
        beta[r] = 0.f;
    }
#pragma unroll
    for (int st = 0; st < 8; st++)
#pragma unroll
        for (int r = 0; r < 4; r++) {
            float al = S[st][r] * den[r];
            S[st][r] = al;
            beta[r] += al * av[st][r];
        }
#pragma unroll
    for (int r = 0; r < 4; r++)
#pragma unroll
        for (int mm = 1; mm < 16; mm <<= 1) beta[r] += __shfl_xor(beta[r], mm);

    // alpha C-layout -> LDS -> A-layout frags (hi only)
#pragma unroll
    for (int st = 0; st < 8; st++)
#pragma unroll
        for (int r = 0; r < 4; r++)
            aL[quad * 4 + r][st * 16 + nl] = S[st][r];
    __syncthreads();
    short8 Ah[4];
#pragma unroll
    for (int ks = 0; ks < 4; ks++) {
        const float* p = &aL[nl][quad * 8 + 32 * ks];
        float4 a0 = *(const float4*)p;
        float4 a1 = *(const float4*)(p + 4);
        float hv[8] = {a0.x, a0.y, a0.z, a0.w, a1.x, a1.y, a1.z, a1.w};
        short8 ah;
#pragma unroll
        for (int j = 0; j < 8; j++) ah[j] = (short)f2us_tr(hv[j]);
        Ah[ks] = ah;
    }

    // preload ALL V frags (32) before the 32 PV MFMAs
    short8 Vh[16], Vl[16];
#pragma unroll
    for (int ks = 0; ks < 4; ks++)
#pragma unroll
        for (int nt = 0; nt < 4; nt++) {
            long dg = (long)(b * 256 + h * DHEAD + nt * 16 + nl);
            Vh[ks * 4 + nt] = *(const short8*)(vThi + dg * NN + quad * 8 + 32 * ks);
            Vl[ks * 4 + nt] = *(const short8*)(vTlo + dg * NN + quad * 8 + 32 * ks);
        }
    float we_d[4];
#pragma unroll
    for (int nt = 0; nt < 4; nt++) we_d[nt] = We[h * DHEAD + nt * 16 + nl];

    fx4 G[4];
#pragma unroll
    for (int nt = 0; nt < 4; nt++) {
        fx4 g;
#pragma unroll
        for (int r = 0; r < 4; r++) g[r] = beta[r] * we_d[nt];
        G[nt] = g;
    }
#pragma unroll
    for (int ks = 0; ks < 4; ks++)
#pragma unroll
        for (int nt = 0; nt < 4; nt++) {
            G[nt] = __builtin_amdgcn_mfma_f32_16x16x32_bf16(Ah[ks], Vh[ks * 4 + nt], G[nt], 0, 0, 0);
            G[nt] = __builtin_amdgcn_mfma_f32_16x16x32_bf16(Ah[ks], Vl[ks * 4 + nt], G[nt], 0, 0, 0);
        }

#pragma unroll
    for (int nt = 0; nt < 4; nt++)
#pragma unroll
        for (int r = 0; r < 4; r++) {
            int gi = (b * NN + t0 + quad * 4 + r) * HD + h * DHEAD + nt * 16 + nl;
            xout[gi] = fmaxf(G[nt][r] + skip[gi], 0.f);
        }
}

// ---------------- K8: gather agent rows -> f32 out ----------------
__global__ void k_gather(const float* x2, const int* agent, float* out) {
    int b = blockIdx.x;
    int c = threadIdx.x;
    out[b * HD + c] = x2[(b * NN + agent[b]) * HD + c];
}

// ---------------- launch ----------------
extern "C" void kernel_launch(void* const* d_in, const int* in_sizes, int n_in,
                              void* d_out, int out_size, void* d_ws, size_t ws_size,
                              hipStream_t stream) {
    float* out = (float*)d_out;
    (void)hipGetLastError();

    bool ok = (n_in == 31) && in_sizes[0] == BB * NN * FF && in_sizes[2] == BB * NN * NN
              && in_sizes[5] == (FF + EE + 1) * HH && in_sizes[13] == HH * HD
              && in_sizes[22] == HD * HD && out_size == BB * HD;
    if (!ok) { k_sent<<<32, 256, 0, stream>>>(out, -30000.f); return; }

    const size_t WS_NEED = (size_t)8912896 * 4;
    if (ws_size < WS_NEED) { k_sent<<<32, 256, 0, stream>>>(out, -20000.f); return; }

    const float* nf    = (const float*)d_in[0];
    const int*   et    = (const int*)d_in[1];
    const float* adj   = (const float*)d_in[2];
    const int*   agent = (const int*)d_in[3];
    const float* emb   = (const float*)d_in[4];
    const float* W1    = (const float*)d_in[5];
    const float* b1    = (const float*)d_in[6];
    const float* g1    = (const float*)d_in[7];
    const float* be1   = (const float*)d_in[8];
    const float* Wh    = (const float*)d_in[9];
    const float* bh    = (const float*)d_in[10];
    const float* gh    = (const float*)d_in[11];
    const float* beh   = (const float*)d_in[12];
    const float* Wq1   = (const float*)d_in[13];
    const float* bq1   = (const float*)d_in[14];
    const float* Wk1   = (const float*)d_in[15];
    const float* bk1   = (const float*)d_in[16];
    const float* Wv1   = (const float*)d_in[17];
    const float* bv1   = (const float*)d_in[18];
    const float* We1   = (const float*)d_in[19];
    const float* Ws1   = (const float*)d_in[20];
    const float* bs1   = (const float*)d_in[21];
    const float* Wq2   = (const float*)d_in[22];
    const float* bq2   = (const float*)d_in[23];
    const float* Wk2   = (const float*)d_in[24];
    const float* bk2   = (const float*)d_in[25];
    const float* Wv2   = (const float*)d_in[26];
    const float* bv2   = (const float*)d_in[27];
    const float* We2   = (const float*)d_in[28];
    const float* Ws2   = (const float*)d_in[29];
    const float* bs2   = (const float*)d_in[30];

    float* ws   = (float*)d_ws;
    float* adjv = ws;                              // 524288 f
    float* base = adjv + BB * NN * NN;             // 524288 f
    float* x0   = base + BB * NN * HH;             // 524288 f
    float* q    = x0 + BB * NN * HH;               // 1048576 f
    float* kreg = q + BB * NN * HD;                // -> khi/klo
    float* vreg = kreg + BB * NN * HD;             // -> vThi/vTlo
    float* skip = vreg + BB * NN * HD;
    float* areg = skip + BB * NN * HD;             // weight planes + adjvT
    float* x1   = areg + BB * NN * HD;
    float* x2   = x1 + BB * NN * HD;

    ushort_t* BhiG = (ushort_t*)q;
    ushort_t* BloG = BhiG + HH * HH;
    float*    W1sW = q + 16384;
    float*    cbW  = q + 16512;

    ushort_t* khi  = (ushort_t*)kreg;
    ushort_t* klo  = khi + BB * NN * HD;
    ushort_t* vThi = (ushort_t*)vreg;
    ushort_t* vTlo = vThi + BB * NN * HD;

    ushort_t* WhA = (ushort_t*)areg;
    ushort_t* WlA = WhA + 4 * 256 * HH;
    ushort_t* WhB = WlA + 4 * 256 * HH;
    ushort_t* WlB = WhB + 4 * 256 * HD;
    float* adjvT  = areg + 393216;

    int fail = 0;
    hipError_t e;
#define CHK(stage) do { e = hipGetLastError(); if (e != hipSuccess && fail == 0) fail = (stage); } while (0)

    k_adjv<<<BB, 256, 0, stream>>>(adj, adjv, adjvT);                                CHK(1);
    k_base<<<BB * NN, HH, 0, stream>>>(nf, et, emb, W1, b1, base, x0);               CHK(2);
    k_prep<<<HH, 64, 0, stream>>>(Wh, g1, be1, bh, BhiG, BloG, W1sW, cbW);           CHK(3);
    k_prepw<<<1024, 64, 0, stream>>>(Wq1, Wk1, Wv1, Ws1, HH, WhA, WlA);              CHK(4);
    k_prepw<<<1024, 64, 0, stream>>>(Wq2, Wk2, Wv2, Ws2, HD, WhB, WlB);              CHK(5);
    k_econv_mfma<<<512, 256, 0, stream>>>(adjv, base, W1, BhiG, BloG, W1sW, cbW,
                                          gh, beh, x0);                              CHK(6);

    k_qkvs_mfma<HH><<<256, 256, 0, stream>>>(x0, WhA, WlA, bq1, bk1, bv1, bs1,
                                             q, skip, khi, klo, vThi, vTlo);         CHK(7);
    k_attn_mfma<<<1024, 64, 0, stream>>>(q, khi, klo, vThi, vTlo, adjvT, We1,
                                         skip, x1);                                  CHK(8);

    k_qkvs_mfma<HD><<<256, 256, 0, stream>>>(x1, WhB, WlB, bq2, bk2, bv2, bs2,
                                             q, skip, khi, klo, vThi, vTlo);         CHK(9);
    k_attn_mfma<<<1024, 64, 0, stream>>>(q, khi, klo, vThi, vTlo, adjvT, We2,
                                         skip, x2);                                  CHK(10);

    k_gather<<<BB, HD, 0, stream>>>(x2, agent, out);                                 CHK(11);
#undef CHK

    if (fail != 0)
        k_sent<<<32, 256, 0, stream>>>(out, -(1000.f + 500.f * (float)fail));
}